// Round 7
// baseline (205.253 us; speedup 1.0000x reference)
//
#include <hip/hip_runtime.h>
#include <math.h>

#define N_ROWS 32768
#define D 256
#define C 16

// workspace layout in floats (dword indices)
#define WS_SUMS_A 0
#define WS_SQ_A   4096
#define WS_SUMS_B 8192
#define WS_SQ_B   12288
#define WS_INV    16384
#define WS_COV    16385
#define WS_CTR    16386   /* int: last-block counter for k_cov5 finisher */
#define WS_COUNTS 16392   /* int[16] */
#define WS_CURSOR 16408   /* int[16] (fallback only) */
#define WS_POFFP  16424   /* int[17] 32-row substep offsets */
#define WS_EOFF   16448   /* int[17] row prefix */
#define WS_INVP   16512   /* float[256] per-(inp,split,cls) inv partials */
#define WS_COVP   17024   /* float[640] per-(task,k0) cov partials */
#define WS_PERM   17920   /* int[32768] */
#define WS_ZERO_FLOATS 16408

#define WS_PSUM   50688   /* [8 split][16 cls][2 inp][512] */
#define WS_HPART  181760  /* int[64*16] per-block hist partials */
#define WS_GPART2 189952  /* packed bf16x2 split partials */
#define GP_TILE2P 2048    /* 64x64 packed as 2048 uints (cols c,c+32) */
#define NTASK     10      /* upper-tri 4x4 of 64x64 blocks */
#define NSPLIT    8
#define KC        2       /* k_cov5 k-split */
#define GP_PER_SPLIT2P (NTASK * C * 2 * GP_TILE2P)   /* 655,360 dwords */
#define RIDX_CAP  1024
#define NEED_A ((size_t)(WS_GPART2 + NSPLIT * GP_PER_SPLIT2P) * 4)   /* ~22 MiB */

typedef __attribute__((ext_vector_type(8))) __bf16 bf16x8;
typedef __attribute__((ext_vector_type(16))) float f32x16;

__device__ inline unsigned bf16_rne(float f) {
    unsigned u = __float_as_uint(f);
    return (u + 0x7fffu + ((u >> 16) & 1u)) >> 16;
}
__device__ inline unsigned pack_bf16(float lo, float hi) {
    return bf16_rne(lo) | (bf16_rne(hi) << 16);
}
// Image: col-major, stride 20 dwords (16B-aligned -> real ds_*_b128),
// k-rotation rot(c)=(c>>1)&12 permutes 4-dword k-blocks per column: breaks
// stride-20's period-8 bank cycle to <=4-way; transparent because write and
// read apply the same rotation. &12 masking keeps alignment provable.
__device__ inline int img_base4(int c, int kd) {   // kd multiple of 4
    return c * 20 + ((kd + ((c >> 1) & 12)) & 12);
}
__device__ inline int img_base2(int c, int kd) {   // kd even (b64 path)
    return c * 20 + ((kd + ((c >> 1) & 12)) & 14);
}
// wave w -> 64x64 task (r,c) in upper triangle of 4x4
__device__ inline void task_rc(int w, int& r, int& c) {
    if (w < 4)      { r = 0; c = w; }
    else if (w < 7) { r = 1; c = w - 3; }
    else if (w < 9) { r = 2; c = w - 5; }
    else            { r = 3; c = 3; }
}

// ---------------- fast path ----------------

// Tiny label histogram: 64 blocks x 512 rows -> hpart[64][C].
// Also resets the k_cov5 finisher counter (runs strictly before it).
__global__ __launch_bounds__(512) void k_hist2(const int* __restrict__ labels,
                                               int* __restrict__ hpart,
                                               int* __restrict__ ctr) {
    __shared__ int h[C];
    const int t = threadIdx.x;
    if (t < C) h[t] = 0;
    __syncthreads();
    if (blockIdx.x == 0 && t == 0) *ctr = 0;
    atomicAdd(&h[labels[blockIdx.x * 512 + t]], 1);
    __syncthreads();
    if (t < C) hpart[blockIdx.x * C + t] = h[t];
}

// Scatter with locally-recomputed scan over the 64 hist partials.
__global__ __launch_bounds__(512) void k_scatter2(const int* __restrict__ labels,
                                                  const int* __restrict__ hpart,
                                                  int* __restrict__ counts,
                                                  int* __restrict__ poffp,
                                                  int* __restrict__ eoffp,
                                                  int* __restrict__ perm) {
    const int t = threadIdx.x;
    const int B = blockIdx.x;             // 0..63, 512 rows each
    __shared__ int lh[C];
    __shared__ int tot[32][C];
    __shared__ int pre[32][C];
    __shared__ int ccnt[C], cpre[C], ceoff[C];
    const int i = B * 512 + t;
    const int lab = labels[i];
    if (t < C) lh[t] = 0;
    const int c = t & 15, seg = t >> 4;   // seg in [0,32): hist blocks 2seg,2seg+1
    {
        const int p0 = 2 * seg, p1 = p0 + 1;
        const int v0 = hpart[p0 * C + c], v1 = hpart[p1 * C + c];
        tot[seg][c] = v0 + v1;
        pre[seg][c] = (p0 < B ? v0 : 0) + (p1 < B ? v1 : 0);
    }
    __syncthreads();
    const int lr = atomicAdd(&lh[lab], 1);
    if (t < C) {
        int s1 = 0, s2 = 0;
        #pragma unroll
        for (int g = 0; g < 32; ++g) { s1 += tot[g][t]; s2 += pre[g][t]; }
        ccnt[t] = s1;
        cpre[t] = s2;
    }
    __syncthreads();
    if (t == 0) {
        int off = 0, po = 0;
        for (int cc = 0; cc < C; ++cc) {
            ceoff[cc] = off;
            if (B == 0) { eoffp[cc] = off; poffp[cc] = po; counts[cc] = ccnt[cc]; }
            off += ccnt[cc];
            po += (ccnt[cc] + 31) >> 5;
        }
        if (B == 0) { eoffp[C] = off; poffp[C] = po; }
    }
    __syncthreads();
    perm[ceoff[lab] + cpre[lab] + lr] = i;
}

// Single-read Gram + balanced fused inv loss: one 640-thread block per
// (split,cls,inp) stages all 256 cols once; 10 waves each own a 64x64 block
// of the 256^2 upper triangle. Class stats ride on the staging loads.
// inv loss: inp==0 blocks handle row-pairs it==0, inp==1 blocks it==1 ->
// every block does exactly 1.5x staging loads (balanced critical path).
// Split partials stored packed bf16x2 (cols c,c+32 share a dword).
__global__ __launch_bounds__(640) void k_gram8(const float* __restrict__ za,
                                               const float* __restrict__ zb,
                                               const int* __restrict__ perm,
                                               const int* __restrict__ counts,
                                               const int* __restrict__ poffp,
                                               const int* __restrict__ eoffp,
                                               float* __restrict__ ws) {
    const int t = threadIdx.x;
    const int split = blockIdx.x;
    const int cls = blockIdx.y, inp = blockIdx.z;
    const float* X = inp ? zb : za;
    const float* Y = inp ? za : zb;      // inv-loss partner input
    const int cnt = counts[cls];
    const int eoff = eoffp[cls];
    const int nsteps = poffp[cls + 1] - poffp[cls];
    const int chunk = (nsteps + NSPLIT - 1) / NSPLIT;
    const int sb = split * chunk;
    const int se = min(sb + chunk, nsteps);

    __shared__ __align__(16) unsigned img[2][5120];   // 40 KB
    __shared__ float sstats[512];
    __shared__ float redI[8];
    __shared__ int ridx[RIDX_CAP];

    for (int i = t; i < 512; i += 640) sstats[i] = 0.f;
    const int nl = (se > sb) ? (se - sb) * 32 : 0;
    for (int i = t; i < nl && i < RIDX_CAP; i += 640) {
        const int gr = sb * 32 + i;
        ridx[i] = (gr < cnt) ? perm[eoff + gr] : -1;
    }
    __syncthreads();

    auto rowidx = [&](int li) -> int {
        if (li < RIDX_CAP) return ridx[li];
        const int gr = sb * 32 + li;
        return (gr < cnt) ? perm[eoff + gr] : -1;
    };

    const int lane = t & 63, w = t >> 6;
    const int cg = lane & 31, q = lane >> 5;
    int tr, tc;
    task_rc(w, tr, tc);
    const bool stg = (t < 512);

    // staging: thread u covers cols 4*(u&63).., row-pairs kp0..kp0+1
    const int lc = 4 * (t & 63);
    const int kp0 = 2 * ((t >> 6) & 7);

    f32x16 acc[2][2];
    #pragma unroll
    for (int i = 0; i < 2; ++i)
        #pragma unroll
        for (int j = 0; j < 2; ++j) acc[i][j] = 0.0f;

    float s1r[4] = {0.f, 0.f, 0.f, 0.f};
    float s2r[4] = {0.f, 0.f, 0.f, 0.f};
    float accI = 0.f;
    float4 f0[2], f1[2];
    float4 p0, p1;     // partner rows for this block's inv half

    auto load_regs = [&](int s) {
        #pragma unroll
        for (int it = 0; it < 2; ++it) {
            const int li = (s - sb) * 32 + 2 * (kp0 + it);
            const int r0 = rowidx(li), r1 = rowidx(li + 1);
            f0[it] = (r0 >= 0) ? *(const float4*)(X + (size_t)r0 * D + lc)
                               : make_float4(0.f, 0.f, 0.f, 0.f);
            f1[it] = (r1 >= 0) ? *(const float4*)(X + (size_t)r1 * D + lc)
                               : make_float4(0.f, 0.f, 0.f, 0.f);
            if (it == inp) {
                p0 = (r0 >= 0) ? *(const float4*)(Y + (size_t)r0 * D + lc)
                               : make_float4(0.f, 0.f, 0.f, 0.f);
                p1 = (r1 >= 0) ? *(const float4*)(Y + (size_t)r1 * D + lc)
                               : make_float4(0.f, 0.f, 0.f, 0.f);
            }
        }
    };
    auto pack_store = [&](int buf) {
        unsigned pw[4][2];
        #pragma unroll
        for (int it = 0; it < 2; ++it) {
            pw[0][it] = pack_bf16(f0[it].x, f1[it].x);
            pw[1][it] = pack_bf16(f0[it].y, f1[it].y);
            pw[2][it] = pack_bf16(f0[it].z, f1[it].z);
            pw[3][it] = pack_bf16(f0[it].w, f1[it].w);
        }
        #pragma unroll
        for (int d = 0; d < 4; ++d)
            *(uint2*)&img[buf][img_base2(lc + d, kp0)] = make_uint2(pw[d][0], pw[d][1]);
        #pragma unroll
        for (int it = 0; it < 2; ++it) {
            s1r[0] += f0[it].x + f1[it].x; s2r[0] += f0[it].x * f0[it].x + f1[it].x * f1[it].x;
            s1r[1] += f0[it].y + f1[it].y; s2r[1] += f0[it].y * f0[it].y + f1[it].y * f1[it].y;
            s1r[2] += f0[it].z + f1[it].z; s2r[2] += f0[it].z * f0[it].z + f1[it].z * f1[it].z;
            s1r[3] += f0[it].w + f1[it].w; s2r[3] += f0[it].w * f0[it].w + f1[it].w * f1[it].w;
        }
        // inv diffs for this block's half (compile-time f index)
        if (inp == 0) {
            float d0, d1;
            d0 = f0[0].x - p0.x; d1 = f1[0].x - p1.x; accI += d0 * d0 + d1 * d1;
            d0 = f0[0].y - p0.y; d1 = f1[0].y - p1.y; accI += d0 * d0 + d1 * d1;
            d0 = f0[0].z - p0.z; d1 = f1[0].z - p1.z; accI += d0 * d0 + d1 * d1;
            d0 = f0[0].w - p0.w; d1 = f1[0].w - p1.w; accI += d0 * d0 + d1 * d1;
        } else {
            float d0, d1;
            d0 = f0[1].x - p0.x; d1 = f1[1].x - p1.x; accI += d0 * d0 + d1 * d1;
            d0 = f0[1].y - p0.y; d1 = f1[1].y - p1.y; accI += d0 * d0 + d1 * d1;
            d0 = f0[1].z - p0.z; d1 = f1[1].z - p1.z; accI += d0 * d0 + d1 * d1;
            d0 = f0[1].w - p0.w; d1 = f1[1].w - p1.w; accI += d0 * d0 + d1 * d1;
        }
    };
    auto frag = [&](int buf, int col, int kd) -> bf16x8 {
        return *(const bf16x8*)&img[buf][img_base4(col, kd)];
    };

    if (sb < se) {
        if (stg) { load_regs(sb); pack_store(0); }
        __syncthreads();
        for (int s = sb; s < se; ++s) {
            const int buf = (s - sb) & 1;
            const bool more = (s + 1 < se);
            if (stg && more) load_regs(s + 1);   // in flight across MFMAs
            #pragma unroll
            for (int h = 0; h < 2; ++h) {
                const int kd = h * 8 + q * 4;
                bf16x8 a0 = frag(buf, tr * 64 + cg, kd);
                bf16x8 a1 = frag(buf, tr * 64 + 32 + cg, kd);
                bf16x8 b0, b1;
                if (tr == tc) { b0 = a0; b1 = a1; }
                else {
                    b0 = frag(buf, tc * 64 + cg, kd);
                    b1 = frag(buf, tc * 64 + 32 + cg, kd);
                }
                acc[0][0] = __builtin_amdgcn_mfma_f32_32x32x16_bf16(a0, b0, acc[0][0], 0, 0, 0);
                acc[0][1] = __builtin_amdgcn_mfma_f32_32x32x16_bf16(a0, b1, acc[0][1], 0, 0, 0);
                acc[1][0] = __builtin_amdgcn_mfma_f32_32x32x16_bf16(a1, b0, acc[1][0], 0, 0, 0);
                acc[1][1] = __builtin_amdgcn_mfma_f32_32x32x16_bf16(a1, b1, acc[1][1], 0, 0, 0);
            }
            if (stg && more) pack_store(buf ^ 1);
            __syncthreads();
        }
    }

    // split-K partial out, packed bf16x2: lane packs (col, col+32) of same row
    unsigned* gp = (unsigned*)ws + WS_GPART2 + (size_t)split * GP_PER_SPLIT2P
                 + (((size_t)cls * 2 + inp) * NTASK + w) * GP_TILE2P;
    #pragma unroll
    for (int i = 0; i < 2; ++i)
        #pragma unroll
        for (int r = 0; r < 16; ++r) {
            const int row = i * 32 + (r & 3) + 8 * (r >> 2) + 4 * q;
            gp[row * 32 + cg] = pack_bf16(acc[i][0][r], acc[i][1][r]);
        }

    if (stg) {
        float v = accI;
        for (int o = 32; o > 0; o >>= 1) v += __shfl_down(v, o, 64);
        if (lane == 0) redI[w] = v;
        #pragma unroll
        for (int d = 0; d < 4; ++d) {
            atomicAdd(&sstats[lc + d],       s1r[d]);
            atomicAdd(&sstats[256 + lc + d], s2r[d]);
        }
    }
    __syncthreads();
    if (t == 0) {
        float s = 0.f;
        #pragma unroll
        for (int k = 0; k < 8; ++k) s += redI[k];
        ws[WS_INVP + (inp * NSPLIT + split) * C + cls] = s;
    }
    const size_t pbase = (((size_t)split * C + cls) * 2 + inp) * 512;
    for (int i = t; i < 512; i += 640) ws[WS_PSUM + pbase + i] = sstats[i];
}

// Split-sum + cov^2 partial + class-stat fold + last-block final reduction.
// b128 loads: each thread pulls one uint4 (4 packed dwords = 8 cov elements)
// from each of the 8 splits as independent in-flight loads -> BW-bound.
// Finisher pattern proven correct in an earlier revision (threadfence +
// atomic counter); final phase runs on the last resident block (no 6th
// dispatch, no launch bubble).
__global__ __launch_bounds__(256) void k_cov5(const int* __restrict__ counts,
                                              float* __restrict__ ws,
                                              float* __restrict__ out) {
    const int t = threadIdx.x;
    const int w = blockIdx.x / KC, k0 = blockIdx.x % KC;
    int tr, tc;
    task_rc(w, tr, tc);
    const int cls = blockIdx.y, inp = blockIdx.z;
    const int cnt = counts[cls];
    const float fc = (float)cnt;
    const float cinv = 1.f / fc, uinv = 1.f / (fc - 1.f);
    const float wgt = (tr == tc) ? 1.f : 2.f;
    __shared__ float Mr[64], Mc[64];
    if (t < 64) {
        float s = 0.f;
        #pragma unroll
        for (int sp = 0; sp < NSPLIT; ++sp)
            s += ws[WS_PSUM + (((size_t)sp * C + cls) * 2 + inp) * 512 + tr * 64 + t];
        Mr[t] = s * cinv;
    } else if (t < 128) {
        const int u = t - 64;
        float s = 0.f;
        #pragma unroll
        for (int sp = 0; sp < NSPLIT; ++sp)
            s += ws[WS_PSUM + (((size_t)sp * C + cls) * 2 + inp) * 512 + tc * 64 + u];
        Mc[u] = s * cinv;
    }
    // designated stats writer for (cls,inp): fold PSUM -> class stats
    if (w == 0 && k0 == 0) {
        float s1 = 0.f, s2 = 0.f;
        #pragma unroll
        for (int sp = 0; sp < NSPLIT; ++sp) {
            const size_t pb = WS_PSUM + (((size_t)sp * C + cls) * 2 + inp) * 512;
            s1 += ws[pb + t];
            s2 += ws[pb + 256 + t];
        }
        ws[(inp ? WS_SUMS_B : WS_SUMS_A) + cls * D + t] = s1;
        ws[(inp ? WS_SQ_B   : WS_SQ_A)   + cls * D + t] = s2;
    }
    __syncthreads();

    const int e0 = k0 * 1024 + t * 4;
    const unsigned* gp0 = (const unsigned*)ws + WS_GPART2
                        + (((size_t)cls * 2 + inp) * NTASK + w) * GP_TILE2P + e0;
    uint4 u4[NSPLIT];
    #pragma unroll
    for (int sp = 0; sp < NSPLIT; ++sp)
        u4[sp] = *(const uint4*)(gp0 + (size_t)sp * GP_PER_SPLIT2P);

    float glo[4] = {0.f, 0.f, 0.f, 0.f};
    float ghi[4] = {0.f, 0.f, 0.f, 0.f};
    #pragma unroll
    for (int sp = 0; sp < NSPLIT; ++sp) {
        const unsigned* uu = (const unsigned*)&u4[sp];
        #pragma unroll
        for (int j = 0; j < 4; ++j) {
            glo[j] += __uint_as_float(uu[j] << 16);
            ghi[j] += __uint_as_float(uu[j] & 0xffff0000u);
        }
    }
    const int row = e0 >> 5, c0 = e0 & 31;
    const float mr = Mr[row];
    float local = 0.f;
    #pragma unroll
    for (int j = 0; j < 4; ++j) {
        const float clo = (glo[j] - fc * mr * Mc[c0 + j]) * uinv;
        const float chi = (ghi[j] - fc * mr * Mc[c0 + j + 32]) * uinv;
        if (!(tr == tc && row == c0 + j))      local += wgt * clo * clo;
        if (!(tr == tc && row == c0 + j + 32)) local += wgt * chi * chi;
    }
    for (int o = 32; o > 0; o >>= 1) local += __shfl_down(local, o, 64);
    __shared__ float red[4];
    if ((t & 63) == 0) red[t >> 6] = local;
    __syncthreads();
    if (t == 0)
        ws[WS_COVP + (((size_t)inp * C + cls) * NTASK + w) * KC + k0] =
            red[0] + red[1] + red[2] + red[3];

    // ---- last-block finisher ----
    __shared__ int isLast;
    __threadfence();
    __syncthreads();
    if (t == 0) {
        const int old = atomicAdd((int*)ws + WS_CTR, 1);
        isLast = (old == NTASK * KC * C * 2 - 1);
    }
    __syncthreads();
    if (!isLast) return;
    __threadfence();

    __shared__ float M[C * D];
    __shared__ float redv[4], redi[4], redc[4], redp[4];
    float vsum = 0.f;
    for (int idx = t; idx < 2 * C * D; idx += 256) {
        const int ip = idx >> 12;
        const int cd = idx & 4095;
        const int cc = cd >> 8;
        const float cn = (float)counts[cc];
        const float s  = ws[(ip ? WS_SUMS_B : WS_SUMS_A) + cd];
        const float sq = ws[(ip ? WS_SQ_B   : WS_SQ_A)   + cd];
        const float mean = s / cn;
        const float var = (sq - cn * mean * mean) / (cn - 1.f);
        vsum += fmaxf(1.f - sqrtf(var + 1e-4f), 0.f);
    }
    float isum = ws[WS_INVP + t];
    float csum = ws[WS_COVP + t] + ws[WS_COVP + 256 + t]
               + ((t < 128) ? ws[WS_COVP + 512 + t] : 0.f);
    for (int cd = t; cd < C * D; cd += 256) {
        const int cc = cd >> 8;
        const float cn = (float)counts[cc];
        M[cd] = 0.5f * (ws[WS_SUMS_A + cd] + ws[WS_SUMS_B + cd]) / cn;
    }
    for (int o = 32; o > 0; o >>= 1) {
        vsum += __shfl_down(vsum, o, 64);
        isum += __shfl_down(isum, o, 64);
        csum += __shfl_down(csum, o, 64);
    }
    if ((t & 63) == 0) {
        redv[t >> 6] = vsum; redi[t >> 6] = isum; redc[t >> 6] = csum;
    }
    __syncthreads();

    const int wv = t >> 6, ln = t & 63;
    float psum = 0.f;
    int p = 0;
    for (int i = 0; i < C; ++i) {
        for (int j = i + 1; j < C; ++j, ++p) {
            if ((p & 3) != wv) continue;
            float d2 = 0.f;
            #pragma unroll
            for (int d = ln; d < D; d += 64) {
                const float df = M[i * D + d] - M[j * D + d];
                d2 += df * df;
            }
            for (int o = 32; o > 0; o >>= 1) d2 += __shfl_down(d2, o, 64);
            if (ln == 0) {
                const float dist = sqrtf(d2);
                const float r = fmaxf(50.f - dist, 0.f);
                psum += r * r;
            }
        }
    }
    if (ln == 0) redp[wv] = psum;
    __syncthreads();

    if (t == 0) {
        const float var_loss = (redv[0] + redv[1] + redv[2] + redv[3]) / 8192.f;
        const float class_loss = (redp[0] + redp[1] + redp[2] + redp[3]) / 120.f;
        const float inv_loss = (redi[0] + redi[1] + redi[2] + redi[3]) / (float)(N_ROWS * D);
        const float cov_loss = 0.5f * (redc[0] + redc[1] + redc[2] + redc[3]) / (float)(C * D);
        out[0] = 25.f * inv_loss + 25.f * var_loss + 1.f * cov_loss + 50.f * class_loss;
    }
}

// ---------------- fallback (tiny ws) ----------------
__global__ __launch_bounds__(512) void k_hist(const int* __restrict__ labels,
                                              int* __restrict__ counts) {
    __shared__ int h[C];
    const int t = threadIdx.x;
    if (t < C) h[t] = 0;
    __syncthreads();
    const int i = blockIdx.x * 512 + t;
    atomicAdd(&h[labels[i]], 1);
    __syncthreads();
    if (t < C) atomicAdd(&counts[t], h[t]);
}

__global__ void k_scan(const int* __restrict__ counts, int* __restrict__ cursor,
                       int* __restrict__ poffp, int* __restrict__ eoffp) {
    if (threadIdx.x == 0) {
        int off = 0, po = 0;
        for (int c = 0; c < C; ++c) {
            cursor[c] = off;
            eoffp[c] = off;
            poffp[c] = po;
            off += counts[c];
            po += (counts[c] + 31) >> 5;
        }
        poffp[C] = po;
        eoffp[C] = off;
    }
}

__global__ __launch_bounds__(512) void k_scatter(const int* __restrict__ labels,
                                                 int* __restrict__ cursor,
                                                 int* __restrict__ perm) {
    __shared__ int lh[C];
    __shared__ int lbase[C];
    const int t = threadIdx.x;
    if (t < C) lh[t] = 0;
    __syncthreads();
    const int i = blockIdx.x * 512 + t;
    const int lab = labels[i];
    const int lr = atomicAdd(&lh[lab], 1);
    __syncthreads();
    if (t < C) lbase[t] = atomicAdd(&cursor[t], lh[t]);
    __syncthreads();
    perm[lbase[lab] + lr] = i;
}

__global__ __launch_bounds__(256) void k_stats(const float* __restrict__ za,
                                               const float* __restrict__ zb,
                                               const int* __restrict__ labels,
                                               float* __restrict__ ws) {
    const int t = threadIdx.x;
    __shared__ float S[4][C * D];
    __shared__ int lab[512];
    for (int i = t; i < 4 * C * D; i += 256) ((float*)S)[i] = 0.f;
    const int r0 = blockIdx.x * 512;
    for (int i = t; i < 512; i += 256) lab[i] = labels[r0 + i];
    __syncthreads();
    float invp = 0.f;
    #pragma unroll 4
    for (int rr = 0; rr < 512; ++rr) {
        const int l = lab[rr];
        const float a = za[(size_t)(r0 + rr) * D + t];
        const float b = zb[(size_t)(r0 + rr) * D + t];
        const float dd = a - b;
        invp += dd * dd;
        S[0][l * D + t] += a;
        S[1][l * D + t] += a * a;
        S[2][l * D + t] += b;
        S[3][l * D + t] += b * b;
    }
    __syncthreads();
    #pragma unroll
    for (int c = 0; c < C; ++c) {
        atomicAdd(&ws[WS_SUMS_A + c * D + t], S[0][c * D + t]);
        atomicAdd(&ws[WS_SQ_A   + c * D + t], S[1][c * D + t]);
        atomicAdd(&ws[WS_SUMS_B + c * D + t], S[2][c * D + t]);
        atomicAdd(&ws[WS_SQ_B   + c * D + t], S[3][c * D + t]);
    }
    for (int o = 32; o > 0; o >>= 1) invp += __shfl_down(invp, o, 64);
    if ((t & 63) == 0) atomicAdd(&ws[WS_INV], invp);
}

#define STR 20
#define KB 32
__global__ __launch_bounds__(256) void k_gram_slow(const float* __restrict__ za,
                                                   const float* __restrict__ zb,
                                                   const int* __restrict__ perm,
                                                   const int* __restrict__ counts,
                                                   float* __restrict__ ws) {
    const int t = threadIdx.x;
    const int tile = blockIdx.x;
    const int tx = tile >> 1, ty = (tile + 1) >> 1;
    const int cls = blockIdx.y;
    const int inp = blockIdx.z;
    const float* X = inp ? zb : za;
    const float* sums = ws + (inp ? WS_SUMS_B : WS_SUMS_A) + cls * D;
    int offs = 0;
    for (int c = 0; c < cls; ++c) offs += counts[c];
    const int cnt = counts[cls];
    const int cm0 = tx * 128, cn0 = ty * 128;
    __shared__ __align__(16) unsigned lds[2][256 * STR];
    const int p = t >> 5, cq = t & 31;
    const int lane = t & 63, w = t >> 6;
    const int wr = w & 1, wc = w >> 1;
    const int cg = lane & 31, q = lane >> 5;
    f32x16 acc[2][2];
    #pragma unroll
    for (int i = 0; i < 2; ++i)
        #pragma unroll
        for (int j = 0; j < 2; ++j) acc[i][j] = 0.0f;
    const int nsteps = (cnt + KB - 1) / KB;
    auto stage = [&](int buf, int k0) {
        #pragma unroll
        for (int ch = 0; ch < 2; ++ch) {
            const int gc = (ch ? cn0 : cm0) + 4 * cq;
            #pragma unroll
            for (int sub = 0; sub < 2; ++sub) {
                const int rr = sub * 16 + 2 * p;
                const int r0 = k0 + rr, r1 = r0 + 1;
                float4 v0 = make_float4(0.f, 0.f, 0.f, 0.f), v1 = v0;
                if (r0 < cnt) v0 = *(const float4*)(X + (size_t)perm[offs + r0] * D + gc);
                if (r1 < cnt) v1 = *(const float4*)(X + (size_t)perm[offs + r1] * D + gc);
                unsigned* dst = &lds[buf][(ch * 128 + 4 * cq) * STR + (rr >> 1)];
                dst[0 * STR] = pack_bf16(v0.x, v1.x);
                dst[1 * STR] = pack_bf16(v0.y, v1.y);
                dst[2 * STR] = pack_bf16(v0.z, v1.z);
                dst[3 * STR] = pack_bf16(v0.w, v1.w);
            }
        }
    };
    auto frag = [&](int buf, int colbase, int h) -> bf16x8 {
        return *(const bf16x8*)&lds[buf][(colbase + cg) * STR + h * 8 + q * 4];
    };
    stage(0, 0);
    for (int s = 0; s < nsteps; ++s) {
        __syncthreads();
        const int buf = s & 1;
        if (s + 1 < nsteps) stage(buf ^ 1, (s + 1) * KB);
        #pragma unroll
        for (int h = 0; h < 2; ++h) {
            bf16x8 a0 = frag(buf, wr * 64, h);
            bf16x8 a1 = frag(buf, wr * 64 + 32, h);
            bf16x8 b0 = frag(buf, 128 + wc * 64, h);
            bf16x8 b1 = frag(buf, 128 + wc * 64 + 32, h);
            acc[0][0] = __builtin_amdgcn_mfma_f32_32x32x16_bf16(a0, b0, acc[0][0], 0, 0, 0);
            acc[0][1] = __builtin_amdgcn_mfma_f32_32x32x16_bf16(a0, b1, acc[0][1], 0, 0, 0);
            acc[1][0] = __builtin_amdgcn_mfma_f32_32x32x16_bf16(a1, b0, acc[1][0], 0, 0, 0);
            acc[1][1] = __builtin_amdgcn_mfma_f32_32x32x16_bf16(a1, b1, acc[1][1], 0, 0, 0);
        }
    }
    const float fc = (float)cnt;
    const float cinv = 1.f / fc, uinv = 1.f / (fc - 1.f);
    const float wgt = (tx == ty) ? 1.f : 2.f;
    float local = 0.f;
    #pragma unroll
    for (int i = 0; i < 2; ++i) {
        #pragma unroll
        for (int j = 0; j < 2; ++j) {
            const int gn = cn0 + wc * 64 + j * 32 + (lane & 31);
            const float mn = sums[gn] * cinv;
            #pragma unroll
            for (int r = 0; r < 16; ++r) {
                const int row = (r & 3) + 8 * (r >> 2) + 4 * q;
                const int gm = cm0 + wr * 64 + i * 32 + row;
                const float cov = (acc[i][j][r] - fc * (sums[gm] * cinv) * mn) * uinv;
                if (gm != gn) local += wgt * cov * cov;
            }
        }
    }
    for (int o = 32; o > 0; o >>= 1) local += __shfl_down(local, o, 64);
    if (lane == 0) atomicAdd(&ws[WS_COV], local);
}

__global__ __launch_bounds__(256) void k_final(const float* __restrict__ ws,
                                               float* __restrict__ out) {
    __shared__ float M[C * D];
    __shared__ float redv[4], redi[4], redc[4], redp[4];
    const int t = threadIdx.x;
    const int* counts = (const int*)ws + WS_COUNTS;

    float vsum = 0.f;
    for (int idx = t; idx < 2 * C * D; idx += 256) {
        const int inp = idx >> 12;
        const int cd = idx & 4095;
        const int c = cd >> 8;
        const float cnt = (float)counts[c];
        const float s  = ws[(inp ? WS_SUMS_B : WS_SUMS_A) + cd];
        const float sq = ws[(inp ? WS_SQ_B   : WS_SQ_A)   + cd];
        const float mean = s / cnt;
        const float var = (sq - cnt * mean * mean) / (cnt - 1.f);
        vsum += fmaxf(1.f - sqrtf(var + 1e-4f), 0.f);
    }
    float isum = (t == 0) ? ws[WS_INV] : 0.f;
    float csum = (t == 0) ? ws[WS_COV] : 0.f;
    for (int cd = t; cd < C * D; cd += 256) {
        const int c = cd >> 8;
        const float cnt = (float)counts[c];
        M[cd] = 0.5f * (ws[WS_SUMS_A + cd] + ws[WS_SUMS_B + cd]) / cnt;
    }
    for (int o = 32; o > 0; o >>= 1) {
        vsum += __shfl_down(vsum, o, 64);
        isum += __shfl_down(isum, o, 64);
        csum += __shfl_down(csum, o, 64);
    }
    if ((t & 63) == 0) {
        redv[t >> 6] = vsum; redi[t >> 6] = isum; redc[t >> 6] = csum;
    }
    __syncthreads();

    const int wv = t >> 6, ln = t & 63;
    float psum = 0.f;
    int p = 0;
    for (int i = 0; i < C; ++i) {
        for (int j = i + 1; j < C; ++j, ++p) {
            if ((p & 3) != wv) continue;
            float d2 = 0.f;
            #pragma unroll
            for (int d = ln; d < D; d += 64) {
                const float df = M[i * D + d] - M[j * D + d];
                d2 += df * df;
            }
            for (int o = 32; o > 0; o >>= 1) d2 += __shfl_down(d2, o, 64);
            if (ln == 0) {
                const float dist = sqrtf(d2);
                const float r = fmaxf(50.f - dist, 0.f);
                psum += r * r;
            }
        }
    }
    if (ln == 0) redp[wv] = psum;
    __syncthreads();

    if (t == 0) {
        const float var_loss = (redv[0] + redv[1] + redv[2] + redv[3]) / 8192.f;
        const float class_loss = (redp[0] + redp[1] + redp[2] + redp[3]) / 120.f;
        const float inv_loss = (redi[0] + redi[1] + redi[2] + redi[3]) / (float)(N_ROWS * D);
        const float cov_loss = 0.5f * (redc[0] + redc[1] + redc[2] + redc[3]) / (float)(C * D);
        out[0] = 25.f * inv_loss + 25.f * var_loss + 1.f * cov_loss + 50.f * class_loss;
    }
}

extern "C" void kernel_launch(void* const* d_in, const int* in_sizes, int n_in,
                              void* d_out, int out_size, void* d_ws, size_t ws_size,
                              hipStream_t stream) {
    const float* za = (const float*)d_in[0];
    const float* zb = (const float*)d_in[1];
    const int* labels = (const int*)d_in[2];
    float* out = (float*)d_out;
    float* ws = (float*)d_ws;
    int* wsi = (int*)d_ws;

    if (ws_size >= NEED_A) {
        // fast path: 4 dispatches (final folded into cov via finisher)
        k_hist2<<<64, 512, 0, stream>>>(labels, wsi + WS_HPART, wsi + WS_CTR);
        k_scatter2<<<64, 512, 0, stream>>>(labels, wsi + WS_HPART, wsi + WS_COUNTS,
                                           wsi + WS_POFFP, wsi + WS_EOFF, wsi + WS_PERM);
        k_gram8<<<dim3(NSPLIT, C, 2), 640, 0, stream>>>(
            za, zb, wsi + WS_PERM, wsi + WS_COUNTS, wsi + WS_POFFP,
            wsi + WS_EOFF, ws);
        k_cov5<<<dim3(NTASK * KC, C, 2), 256, 0, stream>>>(wsi + WS_COUNTS, ws, out);
    } else {
        hipMemsetAsync(d_ws, 0, WS_ZERO_FLOATS * sizeof(float), stream);
        k_hist<<<64, 512, 0, stream>>>(labels, wsi + WS_COUNTS);
        k_scan<<<1, 64, 0, stream>>>(wsi + WS_COUNTS, wsi + WS_CURSOR,
                                     wsi + WS_POFFP, wsi + WS_EOFF);
        k_scatter<<<64, 512, 0, stream>>>(labels, wsi + WS_CURSOR, wsi + WS_PERM);
        k_stats<<<64, 256, 0, stream>>>(za, zb, labels, ws);
        k_gram_slow<<<dim3(3, C, 2), 256, 0, stream>>>(za, zb, wsi + WS_PERM,
                                                       wsi + WS_COUNTS, ws);
        k_final<<<1, 256, 0, stream>>>(ws, out);
    }
}

// Round 8
// 153.522 us; speedup vs baseline: 1.3370x; 1.3370x over previous
//
#include <hip/hip_runtime.h>
#include <math.h>

#define N_ROWS 32768
#define D 256
#define C 16

// workspace layout in floats (dword indices)
#define WS_SUMS_A 0
#define WS_SQ_A   4096
#define WS_SUMS_B 8192
#define WS_SQ_B   12288
#define WS_INV    16384
#define WS_COV    16385
#define WS_COUNTS 16392   /* int[16] */
#define WS_CURSOR 16408   /* int[16] (fallback only) */
#define WS_POFFP  16424   /* int[17] 32-row substep offsets */
#define WS_EOFF   16448   /* int[17] row prefix */
#define WS_INVP   16512   /* float[256] per-(inp,split,cls) inv partials */
#define WS_COVP   17024   /* float[640] per-(task,k0) cov partials */
#define WS_PERM   17920   /* int[32768] */
#define WS_ZERO_FLOATS 16408

#define WS_PSUM   50688   /* [8 split][16 cls][2 inp][512] */
#define WS_HPART  181760  /* int[64*16] per-block hist partials */
#define WS_GPART2 189952  /* packed bf16x2 split partials */
#define GP_TILE2P 2048    /* 64x64 packed as 2048 uints (cols c,c+32) */
#define NTASK     10      /* upper-tri 4x4 of 64x64 blocks */
#define NSPLIT    8
#define KC        2       /* k_cov4 k-split */
#define GP_PER_SPLIT2P (NTASK * C * 2 * GP_TILE2P)   /* 655,360 dwords */
#define RIDX_CAP  1024
#define NEED_A ((size_t)(WS_GPART2 + NSPLIT * GP_PER_SPLIT2P) * 4)   /* ~22 MiB */

typedef __attribute__((ext_vector_type(8))) __bf16 bf16x8;
typedef __attribute__((ext_vector_type(16))) float f32x16;

__device__ inline unsigned bf16_rne(float f) {
    unsigned u = __float_as_uint(f);
    return (u + 0x7fffu + ((u >> 16) & 1u)) >> 16;
}
__device__ inline unsigned pack_bf16(float lo, float hi) {
    return bf16_rne(lo) | (bf16_rne(hi) << 16);
}
// Image: col-major, stride 20 dwords (16B-aligned -> real ds_*_b128),
// k-rotation rot(c)=(c>>1)&12 permutes 4-dword k-blocks per column: breaks
// stride-20's period-8 bank cycle to <=4-way; transparent because write and
// read apply the same rotation. &12 masking keeps alignment provable.
__device__ inline int img_base4(int c, int kd) {   // kd multiple of 4
    return c * 20 + ((kd + ((c >> 1) & 12)) & 12);
}
__device__ inline int img_base2(int c, int kd) {   // kd even (b64 path)
    return c * 20 + ((kd + ((c >> 1) & 12)) & 14);
}
// wave w -> 64x64 task (r,c) in upper triangle of 4x4
__device__ inline void task_rc(int w, int& r, int& c) {
    if (w < 4)      { r = 0; c = w; }
    else if (w < 7) { r = 1; c = w - 3; }
    else if (w < 9) { r = 2; c = w - 5; }
    else            { r = 3; c = 3; }
}

// ---------------- fast path ----------------

// Tiny label histogram: 64 blocks x 512 rows -> hpart[64][C].
__global__ __launch_bounds__(512) void k_hist2(const int* __restrict__ labels,
                                               int* __restrict__ hpart) {
    __shared__ int h[C];
    const int t = threadIdx.x;
    if (t < C) h[t] = 0;
    __syncthreads();
    atomicAdd(&h[labels[blockIdx.x * 512 + t]], 1);
    __syncthreads();
    if (t < C) hpart[blockIdx.x * C + t] = h[t];
}

// Scatter with locally-recomputed scan over the 64 hist partials.
__global__ __launch_bounds__(512) void k_scatter2(const int* __restrict__ labels,
                                                  const int* __restrict__ hpart,
                                                  int* __restrict__ counts,
                                                  int* __restrict__ poffp,
                                                  int* __restrict__ eoffp,
                                                  int* __restrict__ perm) {
    const int t = threadIdx.x;
    const int B = blockIdx.x;             // 0..63, 512 rows each
    __shared__ int lh[C];
    __shared__ int tot[32][C];
    __shared__ int pre[32][C];
    __shared__ int ccnt[C], cpre[C], ceoff[C];
    const int i = B * 512 + t;
    const int lab = labels[i];
    if (t < C) lh[t] = 0;
    const int c = t & 15, seg = t >> 4;   // seg in [0,32): hist blocks 2seg,2seg+1
    {
        const int p0 = 2 * seg, p1 = p0 + 1;
        const int v0 = hpart[p0 * C + c], v1 = hpart[p1 * C + c];
        tot[seg][c] = v0 + v1;
        pre[seg][c] = (p0 < B ? v0 : 0) + (p1 < B ? v1 : 0);
    }
    __syncthreads();
    const int lr = atomicAdd(&lh[lab], 1);
    if (t < C) {
        int s1 = 0, s2 = 0;
        #pragma unroll
        for (int g = 0; g < 32; ++g) { s1 += tot[g][t]; s2 += pre[g][t]; }
        ccnt[t] = s1;
        cpre[t] = s2;
    }
    __syncthreads();
    if (t == 0) {
        int off = 0, po = 0;
        for (int cc = 0; cc < C; ++cc) {
            ceoff[cc] = off;
            if (B == 0) { eoffp[cc] = off; poffp[cc] = po; counts[cc] = ccnt[cc]; }
            off += ccnt[cc];
            po += (ccnt[cc] + 31) >> 5;
        }
        if (B == 0) { eoffp[C] = off; poffp[C] = po; }
    }
    __syncthreads();
    perm[ceoff[lab] + cpre[lab] + lr] = i;
}

// Single-read Gram + balanced fused inv loss: one 640-thread block per
// (split,cls,inp) stages all 256 cols once; 10 waves each own a 64x64 block
// of the 256^2 upper triangle. Class stats ride on the staging loads.
// inv loss: inp==0 blocks handle row-pairs it==0, inp==1 blocks it==1 ->
// every block does exactly 1.5x staging loads (balanced critical path).
// Split partials stored packed bf16x2 (cols c,c+32 share a dword).
__global__ __launch_bounds__(640) void k_gram8(const float* __restrict__ za,
                                               const float* __restrict__ zb,
                                               const int* __restrict__ perm,
                                               const int* __restrict__ counts,
                                               const int* __restrict__ poffp,
                                               const int* __restrict__ eoffp,
                                               float* __restrict__ ws) {
    const int t = threadIdx.x;
    const int split = blockIdx.x;
    const int cls = blockIdx.y, inp = blockIdx.z;
    const float* X = inp ? zb : za;
    const float* Y = inp ? za : zb;      // inv-loss partner input
    const int cnt = counts[cls];
    const int eoff = eoffp[cls];
    const int nsteps = poffp[cls + 1] - poffp[cls];
    const int chunk = (nsteps + NSPLIT - 1) / NSPLIT;
    const int sb = split * chunk;
    const int se = min(sb + chunk, nsteps);

    __shared__ __align__(16) unsigned img[2][5120];   // 40 KB
    __shared__ float sstats[512];
    __shared__ float redI[8];
    __shared__ int ridx[RIDX_CAP];

    for (int i = t; i < 512; i += 640) sstats[i] = 0.f;
    const int nl = (se > sb) ? (se - sb) * 32 : 0;
    for (int i = t; i < nl && i < RIDX_CAP; i += 640) {
        const int gr = sb * 32 + i;
        ridx[i] = (gr < cnt) ? perm[eoff + gr] : -1;
    }
    __syncthreads();

    auto rowidx = [&](int li) -> int {
        if (li < RIDX_CAP) return ridx[li];
        const int gr = sb * 32 + li;
        return (gr < cnt) ? perm[eoff + gr] : -1;
    };

    const int lane = t & 63, w = t >> 6;
    const int cg = lane & 31, q = lane >> 5;
    int tr, tc;
    task_rc(w, tr, tc);
    const bool stg = (t < 512);

    // staging: thread u covers cols 4*(u&63).., row-pairs kp0..kp0+1
    const int lc = 4 * (t & 63);
    const int kp0 = 2 * ((t >> 6) & 7);

    f32x16 acc[2][2];
    #pragma unroll
    for (int i = 0; i < 2; ++i)
        #pragma unroll
        for (int j = 0; j < 2; ++j) acc[i][j] = 0.0f;

    float s1r[4] = {0.f, 0.f, 0.f, 0.f};
    float s2r[4] = {0.f, 0.f, 0.f, 0.f};
    float accI = 0.f;
    float4 f0[2], f1[2];
    float4 p0, p1;     // partner rows for this block's inv half

    auto load_regs = [&](int s) {
        #pragma unroll
        for (int it = 0; it < 2; ++it) {
            const int li = (s - sb) * 32 + 2 * (kp0 + it);
            const int r0 = rowidx(li), r1 = rowidx(li + 1);
            f0[it] = (r0 >= 0) ? *(const float4*)(X + (size_t)r0 * D + lc)
                               : make_float4(0.f, 0.f, 0.f, 0.f);
            f1[it] = (r1 >= 0) ? *(const float4*)(X + (size_t)r1 * D + lc)
                               : make_float4(0.f, 0.f, 0.f, 0.f);
            if (it == inp) {
                p0 = (r0 >= 0) ? *(const float4*)(Y + (size_t)r0 * D + lc)
                               : make_float4(0.f, 0.f, 0.f, 0.f);
                p1 = (r1 >= 0) ? *(const float4*)(Y + (size_t)r1 * D + lc)
                               : make_float4(0.f, 0.f, 0.f, 0.f);
            }
        }
    };
    auto pack_store = [&](int buf) {
        unsigned pw[4][2];
        #pragma unroll
        for (int it = 0; it < 2; ++it) {
            pw[0][it] = pack_bf16(f0[it].x, f1[it].x);
            pw[1][it] = pack_bf16(f0[it].y, f1[it].y);
            pw[2][it] = pack_bf16(f0[it].z, f1[it].z);
            pw[3][it] = pack_bf16(f0[it].w, f1[it].w);
        }
        #pragma unroll
        for (int d = 0; d < 4; ++d)
            *(uint2*)&img[buf][img_base2(lc + d, kp0)] = make_uint2(pw[d][0], pw[d][1]);
        #pragma unroll
        for (int it = 0; it < 2; ++it) {
            s1r[0] += f0[it].x + f1[it].x; s2r[0] += f0[it].x * f0[it].x + f1[it].x * f1[it].x;
            s1r[1] += f0[it].y + f1[it].y; s2r[1] += f0[it].y * f0[it].y + f1[it].y * f1[it].y;
            s1r[2] += f0[it].z + f1[it].z; s2r[2] += f0[it].z * f0[it].z + f1[it].z * f1[it].z;
            s1r[3] += f0[it].w + f1[it].w; s2r[3] += f0[it].w * f0[it].w + f1[it].w * f1[it].w;
        }
        // inv diffs for this block's half (compile-time f index)
        if (inp == 0) {
            float d0, d1;
            d0 = f0[0].x - p0.x; d1 = f1[0].x - p1.x; accI += d0 * d0 + d1 * d1;
            d0 = f0[0].y - p0.y; d1 = f1[0].y - p1.y; accI += d0 * d0 + d1 * d1;
            d0 = f0[0].z - p0.z; d1 = f1[0].z - p1.z; accI += d0 * d0 + d1 * d1;
            d0 = f0[0].w - p0.w; d1 = f1[0].w - p1.w; accI += d0 * d0 + d1 * d1;
        } else {
            float d0, d1;
            d0 = f0[1].x - p0.x; d1 = f1[1].x - p1.x; accI += d0 * d0 + d1 * d1;
            d0 = f0[1].y - p0.y; d1 = f1[1].y - p1.y; accI += d0 * d0 + d1 * d1;
            d0 = f0[1].z - p0.z; d1 = f1[1].z - p1.z; accI += d0 * d0 + d1 * d1;
            d0 = f0[1].w - p0.w; d1 = f1[1].w - p1.w; accI += d0 * d0 + d1 * d1;
        }
    };
    auto frag = [&](int buf, int col, int kd) -> bf16x8 {
        return *(const bf16x8*)&img[buf][img_base4(col, kd)];
    };

    if (sb < se) {
        if (stg) { load_regs(sb); pack_store(0); }
        __syncthreads();
        for (int s = sb; s < se; ++s) {
            const int buf = (s - sb) & 1;
            const bool more = (s + 1 < se);
            if (stg && more) load_regs(s + 1);   // in flight across MFMAs
            #pragma unroll
            for (int h = 0; h < 2; ++h) {
                const int kd = h * 8 + q * 4;
                bf16x8 a0 = frag(buf, tr * 64 + cg, kd);
                bf16x8 a1 = frag(buf, tr * 64 + 32 + cg, kd);
                bf16x8 b0, b1;
                if (tr == tc) { b0 = a0; b1 = a1; }
                else {
                    b0 = frag(buf, tc * 64 + cg, kd);
                    b1 = frag(buf, tc * 64 + 32 + cg, kd);
                }
                acc[0][0] = __builtin_amdgcn_mfma_f32_32x32x16_bf16(a0, b0, acc[0][0], 0, 0, 0);
                acc[0][1] = __builtin_amdgcn_mfma_f32_32x32x16_bf16(a0, b1, acc[0][1], 0, 0, 0);
                acc[1][0] = __builtin_amdgcn_mfma_f32_32x32x16_bf16(a1, b0, acc[1][0], 0, 0, 0);
                acc[1][1] = __builtin_amdgcn_mfma_f32_32x32x16_bf16(a1, b1, acc[1][1], 0, 0, 0);
            }
            if (stg && more) pack_store(buf ^ 1);
            __syncthreads();
        }
    }

    // split-K partial out, packed bf16x2: lane packs (col, col+32) of same row
    unsigned* gp = (unsigned*)ws + WS_GPART2 + (size_t)split * GP_PER_SPLIT2P
                 + (((size_t)cls * 2 + inp) * NTASK + w) * GP_TILE2P;
    #pragma unroll
    for (int i = 0; i < 2; ++i)
        #pragma unroll
        for (int r = 0; r < 16; ++r) {
            const int row = i * 32 + (r & 3) + 8 * (r >> 2) + 4 * q;
            gp[row * 32 + cg] = pack_bf16(acc[i][0][r], acc[i][1][r]);
        }

    if (stg) {
        float v = accI;
        for (int o = 32; o > 0; o >>= 1) v += __shfl_down(v, o, 64);
        if (lane == 0) redI[w] = v;
        #pragma unroll
        for (int d = 0; d < 4; ++d) {
            atomicAdd(&sstats[lc + d],       s1r[d]);
            atomicAdd(&sstats[256 + lc + d], s2r[d]);
        }
    }
    __syncthreads();
    if (t == 0) {
        float s = 0.f;
        #pragma unroll
        for (int k = 0; k < 8; ++k) s += redI[k];
        ws[WS_INVP + (inp * NSPLIT + split) * C + cls] = s;
    }
    const size_t pbase = (((size_t)split * C + cls) * 2 + inp) * 512;
    for (int i = t; i < 512; i += 640) ws[WS_PSUM + pbase + i] = sstats[i];
}

// Split-sum + cov^2 partial + class-stat fold. b128 loads: each thread pulls
// one uint4 (4 packed dwords = 8 cov elements) from each of the 8 splits as
// independent in-flight loads -> BW-bound, not latency-bound.
__global__ __launch_bounds__(256) void k_cov4(const int* __restrict__ counts,
                                              float* __restrict__ ws) {
    const int t = threadIdx.x;
    const int w = blockIdx.x / KC, k0 = blockIdx.x % KC;
    int tr, tc;
    task_rc(w, tr, tc);
    const int cls = blockIdx.y, inp = blockIdx.z;
    const int cnt = counts[cls];
    const float fc = (float)cnt;
    const float cinv = 1.f / fc, uinv = 1.f / (fc - 1.f);
    const float wgt = (tr == tc) ? 1.f : 2.f;
    __shared__ float Mr[64], Mc[64];
    if (t < 64) {
        float s = 0.f;
        #pragma unroll
        for (int sp = 0; sp < NSPLIT; ++sp)
            s += ws[WS_PSUM + (((size_t)sp * C + cls) * 2 + inp) * 512 + tr * 64 + t];
        Mr[t] = s * cinv;
    } else if (t < 128) {
        const int u = t - 64;
        float s = 0.f;
        #pragma unroll
        for (int sp = 0; sp < NSPLIT; ++sp)
            s += ws[WS_PSUM + (((size_t)sp * C + cls) * 2 + inp) * 512 + tc * 64 + u];
        Mc[u] = s * cinv;
    }
    // designated stats writer for (cls,inp): fold PSUM -> class stats
    if (w == 0 && k0 == 0) {
        float s1 = 0.f, s2 = 0.f;
        #pragma unroll
        for (int sp = 0; sp < NSPLIT; ++sp) {
            const size_t pb = WS_PSUM + (((size_t)sp * C + cls) * 2 + inp) * 512;
            s1 += ws[pb + t];
            s2 += ws[pb + 256 + t];
        }
        ws[(inp ? WS_SUMS_B : WS_SUMS_A) + cls * D + t] = s1;
        ws[(inp ? WS_SQ_B   : WS_SQ_A)   + cls * D + t] = s2;
    }
    __syncthreads();

    const int e0 = k0 * 1024 + t * 4;
    const unsigned* gp0 = (const unsigned*)ws + WS_GPART2
                        + (((size_t)cls * 2 + inp) * NTASK + w) * GP_TILE2P + e0;
    uint4 u4[NSPLIT];
    #pragma unroll
    for (int sp = 0; sp < NSPLIT; ++sp)
        u4[sp] = *(const uint4*)(gp0 + (size_t)sp * GP_PER_SPLIT2P);

    float glo[4] = {0.f, 0.f, 0.f, 0.f};
    float ghi[4] = {0.f, 0.f, 0.f, 0.f};
    #pragma unroll
    for (int sp = 0; sp < NSPLIT; ++sp) {
        const unsigned* uu = (const unsigned*)&u4[sp];
        #pragma unroll
        for (int j = 0; j < 4; ++j) {
            glo[j] += __uint_as_float(uu[j] << 16);
            ghi[j] += __uint_as_float(uu[j] & 0xffff0000u);
        }
    }
    const int row = e0 >> 5, c0 = e0 & 31;
    const float mr = Mr[row];
    float local = 0.f;
    #pragma unroll
    for (int j = 0; j < 4; ++j) {
        const float clo = (glo[j] - fc * mr * Mc[c0 + j]) * uinv;
        const float chi = (ghi[j] - fc * mr * Mc[c0 + j + 32]) * uinv;
        if (!(tr == tc && row == c0 + j))      local += wgt * clo * clo;
        if (!(tr == tc && row == c0 + j + 32)) local += wgt * chi * chi;
    }
    for (int o = 32; o > 0; o >>= 1) local += __shfl_down(local, o, 64);
    __shared__ float red[4];
    if ((t & 63) == 0) red[t >> 6] = local;
    __syncthreads();
    if (t == 0)
        ws[WS_COVP + (((size_t)inp * C + cls) * NTASK + w) * KC + k0] =
            red[0] + red[1] + red[2] + red[3];
}

// ---------------- fallback (tiny ws) ----------------
__global__ __launch_bounds__(512) void k_hist(const int* __restrict__ labels,
                                              int* __restrict__ counts) {
    __shared__ int h[C];
    const int t = threadIdx.x;
    if (t < C) h[t] = 0;
    __syncthreads();
    const int i = blockIdx.x * 512 + t;
    atomicAdd(&h[labels[i]], 1);
    __syncthreads();
    if (t < C) atomicAdd(&counts[t], h[t]);
}

__global__ void k_scan(const int* __restrict__ counts, int* __restrict__ cursor,
                       int* __restrict__ poffp, int* __restrict__ eoffp) {
    if (threadIdx.x == 0) {
        int off = 0, po = 0;
        for (int c = 0; c < C; ++c) {
            cursor[c] = off;
            eoffp[c] = off;
            poffp[c] = po;
            off += counts[c];
            po += (counts[c] + 31) >> 5;
        }
        poffp[C] = po;
        eoffp[C] = off;
    }
}

__global__ __launch_bounds__(512) void k_scatter(const int* __restrict__ labels,
                                                 int* __restrict__ cursor,
                                                 int* __restrict__ perm) {
    __shared__ int lh[C];
    __shared__ int lbase[C];
    const int t = threadIdx.x;
    if (t < C) lh[t] = 0;
    __syncthreads();
    const int i = blockIdx.x * 512 + t;
    const int lab = labels[i];
    const int lr = atomicAdd(&lh[lab], 1);
    __syncthreads();
    if (t < C) lbase[t] = atomicAdd(&cursor[t], lh[t]);
    __syncthreads();
    perm[lbase[lab] + lr] = i;
}

__global__ __launch_bounds__(256) void k_stats(const float* __restrict__ za,
                                               const float* __restrict__ zb,
                                               const int* __restrict__ labels,
                                               float* __restrict__ ws) {
    const int t = threadIdx.x;
    __shared__ float S[4][C * D];
    __shared__ int lab[512];
    for (int i = t; i < 4 * C * D; i += 256) ((float*)S)[i] = 0.f;
    const int r0 = blockIdx.x * 512;
    for (int i = t; i < 512; i += 256) lab[i] = labels[r0 + i];
    __syncthreads();
    float invp = 0.f;
    #pragma unroll 4
    for (int rr = 0; rr < 512; ++rr) {
        const int l = lab[rr];
        const float a = za[(size_t)(r0 + rr) * D + t];
        const float b = zb[(size_t)(r0 + rr) * D + t];
        const float dd = a - b;
        invp += dd * dd;
        S[0][l * D + t] += a;
        S[1][l * D + t] += a * a;
        S[2][l * D + t] += b;
        S[3][l * D + t] += b * b;
    }
    __syncthreads();
    #pragma unroll
    for (int c = 0; c < C; ++c) {
        atomicAdd(&ws[WS_SUMS_A + c * D + t], S[0][c * D + t]);
        atomicAdd(&ws[WS_SQ_A   + c * D + t], S[1][c * D + t]);
        atomicAdd(&ws[WS_SUMS_B + c * D + t], S[2][c * D + t]);
        atomicAdd(&ws[WS_SQ_B   + c * D + t], S[3][c * D + t]);
    }
    for (int o = 32; o > 0; o >>= 1) invp += __shfl_down(invp, o, 64);
    if ((t & 63) == 0) atomicAdd(&ws[WS_INV], invp);
}

#define STR 20
#define KB 32
__global__ __launch_bounds__(256) void k_gram_slow(const float* __restrict__ za,
                                                   const float* __restrict__ zb,
                                                   const int* __restrict__ perm,
                                                   const int* __restrict__ counts,
                                                   float* __restrict__ ws) {
    const int t = threadIdx.x;
    const int tile = blockIdx.x;
    const int tx = tile >> 1, ty = (tile + 1) >> 1;
    const int cls = blockIdx.y;
    const int inp = blockIdx.z;
    const float* X = inp ? zb : za;
    const float* sums = ws + (inp ? WS_SUMS_B : WS_SUMS_A) + cls * D;
    int offs = 0;
    for (int c = 0; c < cls; ++c) offs += counts[c];
    const int cnt = counts[cls];
    const int cm0 = tx * 128, cn0 = ty * 128;
    __shared__ __align__(16) unsigned lds[2][256 * STR];
    const int p = t >> 5, cq = t & 31;
    const int lane = t & 63, w = t >> 6;
    const int wr = w & 1, wc = w >> 1;
    const int cg = lane & 31, q = lane >> 5;
    f32x16 acc[2][2];
    #pragma unroll
    for (int i = 0; i < 2; ++i)
        #pragma unroll
        for (int j = 0; j < 2; ++j) acc[i][j] = 0.0f;
    const int nsteps = (cnt + KB - 1) / KB;
    auto stage = [&](int buf, int k0) {
        #pragma unroll
        for (int ch = 0; ch < 2; ++ch) {
            const int gc = (ch ? cn0 : cm0) + 4 * cq;
            #pragma unroll
            for (int sub = 0; sub < 2; ++sub) {
                const int rr = sub * 16 + 2 * p;
                const int r0 = k0 + rr, r1 = r0 + 1;
                float4 v0 = make_float4(0.f, 0.f, 0.f, 0.f), v1 = v0;
                if (r0 < cnt) v0 = *(const float4*)(X + (size_t)perm[offs + r0] * D + gc);
                if (r1 < cnt) v1 = *(const float4*)(X + (size_t)perm[offs + r1] * D + gc);
                unsigned* dst = &lds[buf][(ch * 128 + 4 * cq) * STR + (rr >> 1)];
                dst[0 * STR] = pack_bf16(v0.x, v1.x);
                dst[1 * STR] = pack_bf16(v0.y, v1.y);
                dst[2 * STR] = pack_bf16(v0.z, v1.z);
                dst[3 * STR] = pack_bf16(v0.w, v1.w);
            }
        }
    };
    auto frag = [&](int buf, int colbase, int h) -> bf16x8 {
        return *(const bf16x8*)&lds[buf][(colbase + cg) * STR + h * 8 + q * 4];
    };
    stage(0, 0);
    for (int s = 0; s < nsteps; ++s) {
        __syncthreads();
        const int buf = s & 1;
        if (s + 1 < nsteps) stage(buf ^ 1, (s + 1) * KB);
        #pragma unroll
        for (int h = 0; h < 2; ++h) {
            bf16x8 a0 = frag(buf, wr * 64, h);
            bf16x8 a1 = frag(buf, wr * 64 + 32, h);
            bf16x8 b0 = frag(buf, 128 + wc * 64, h);
            bf16x8 b1 = frag(buf, 128 + wc * 64 + 32, h);
            acc[0][0] = __builtin_amdgcn_mfma_f32_32x32x16_bf16(a0, b0, acc[0][0], 0, 0, 0);
            acc[0][1] = __builtin_amdgcn_mfma_f32_32x32x16_bf16(a0, b1, acc[0][1], 0, 0, 0);
            acc[1][0] = __builtin_amdgcn_mfma_f32_32x32x16_bf16(a1, b0, acc[1][0], 0, 0, 0);
            acc[1][1] = __builtin_amdgcn_mfma_f32_32x32x16_bf16(a1, b1, acc[1][1], 0, 0, 0);
        }
    }
    const float fc = (float)cnt;
    const float cinv = 1.f / fc, uinv = 1.f / (fc - 1.f);
    const float wgt = (tx == ty) ? 1.f : 2.f;
    float local = 0.f;
    #pragma unroll
    for (int i = 0; i < 2; ++i) {
        #pragma unroll
        for (int j = 0; j < 2; ++j) {
            const int gn = cn0 + wc * 64 + j * 32 + (lane & 31);
            const float mn = sums[gn] * cinv;
            #pragma unroll
            for (int r = 0; r < 16; ++r) {
                const int row = (r & 3) + 8 * (r >> 2) + 4 * q;
                const int gm = cm0 + wr * 64 + i * 32 + row;
                const float cov = (acc[i][j][r] - fc * (sums[gm] * cinv) * mn) * uinv;
                if (gm != gn) local += wgt * cov * cov;
            }
        }
    }
    for (int o = 32; o > 0; o >>= 1) local += __shfl_down(local, o, 64);
    if (lane == 0) atomicAdd(&ws[WS_COV], local);
}

__global__ __launch_bounds__(256) void k_final(const float* __restrict__ ws,
                                               float* __restrict__ out,
                                               int fast) {
    __shared__ float M[C * D];
    __shared__ float redv[4], redi[4], redc[4], redp[4];
    const int t = threadIdx.x;
    const int* counts = (const int*)ws + WS_COUNTS;

    float vsum = 0.f;
    for (int idx = t; idx < 2 * C * D; idx += 256) {
        const int inp = idx >> 12;
        const int cd = idx & 4095;
        const int c = cd >> 8;
        const float cnt = (float)counts[c];
        const float s  = ws[(inp ? WS_SUMS_B : WS_SUMS_A) + cd];
        const float sq = ws[(inp ? WS_SQ_B   : WS_SQ_A)   + cd];
        const float mean = s / cnt;
        const float var = (sq - cnt * mean * mean) / (cnt - 1.f);
        vsum += fmaxf(1.f - sqrtf(var + 1e-4f), 0.f);
    }
    float isum, csum;
    if (fast) {
        isum = ws[WS_INVP + t];   // 256 per-(inp,split,cls) partials
        csum = ws[WS_COVP + t] + ws[WS_COVP + 256 + t]
             + ((t < 128) ? ws[WS_COVP + 512 + t] : 0.f);
    } else {
        isum = (t == 0) ? ws[WS_INV] : 0.f;
        csum = (t == 0) ? ws[WS_COV] : 0.f;
    }
    for (int cd = t; cd < C * D; cd += 256) {
        const int c = cd >> 8;
        const float cnt = (float)counts[c];
        M[cd] = 0.5f * (ws[WS_SUMS_A + cd] + ws[WS_SUMS_B + cd]) / cnt;
    }
    for (int o = 32; o > 0; o >>= 1) {
        vsum += __shfl_down(vsum, o, 64);
        isum += __shfl_down(isum, o, 64);
        csum += __shfl_down(csum, o, 64);
    }
    if ((t & 63) == 0) {
        redv[t >> 6] = vsum; redi[t >> 6] = isum; redc[t >> 6] = csum;
    }
    __syncthreads();

    const int wv = t >> 6, ln = t & 63;
    float psum = 0.f;
    int p = 0;
    for (int i = 0; i < C; ++i) {
        for (int j = i + 1; j < C; ++j, ++p) {
            if ((p & 3) != wv) continue;
            float d2 = 0.f;
            #pragma unroll
            for (int d = ln; d < D; d += 64) {
                const float df = M[i * D + d] - M[j * D + d];
                d2 += df * df;
            }
            for (int o = 32; o > 0; o >>= 1) d2 += __shfl_down(d2, o, 64);
            if (ln == 0) {
                const float dist = sqrtf(d2);
                const float r = fmaxf(50.f - dist, 0.f);
                psum += r * r;
            }
        }
    }
    if (ln == 0) redp[wv] = psum;
    __syncthreads();

    if (t == 0) {
        const float var_loss = (redv[0] + redv[1] + redv[2] + redv[3]) / 8192.f;
        const float class_loss = (redp[0] + redp[1] + redp[2] + redp[3]) / 120.f;
        const float inv_loss = (redi[0] + redi[1] + redi[2] + redi[3]) / (float)(N_ROWS * D);
        const float cov_loss = 0.5f * (redc[0] + redc[1] + redc[2] + redc[3]) / (float)(C * D);
        out[0] = 25.f * inv_loss + 25.f * var_loss + 1.f * cov_loss + 50.f * class_loss;
    }
}

extern "C" void kernel_launch(void* const* d_in, const int* in_sizes, int n_in,
                              void* d_out, int out_size, void* d_ws, size_t ws_size,
                              hipStream_t stream) {
    const float* za = (const float*)d_in[0];
    const float* zb = (const float*)d_in[1];
    const int* labels = (const int*)d_in[2];
    float* out = (float*)d_out;
    float* ws = (float*)d_ws;
    int* wsi = (int*)d_ws;

    if (ws_size >= NEED_A) {
        // fast path: 5 dispatches (balanced inv fusion in gram)
        // NOTE: in-kernel last-block finisher is a measured anti-pattern here
        // (2x experiments: +60..85 us from device-scope threadfence + VGPR
        // pressure de-vectorizing the split loads). Kernel boundary = cheap fence.
        k_hist2<<<64, 512, 0, stream>>>(labels, wsi + WS_HPART);
        k_scatter2<<<64, 512, 0, stream>>>(labels, wsi + WS_HPART, wsi + WS_COUNTS,
                                           wsi + WS_POFFP, wsi + WS_EOFF, wsi + WS_PERM);
        k_gram8<<<dim3(NSPLIT, C, 2), 640, 0, stream>>>(
            za, zb, wsi + WS_PERM, wsi + WS_COUNTS, wsi + WS_POFFP,
            wsi + WS_EOFF, ws);
        k_cov4<<<dim3(NTASK * KC, C, 2), 256, 0, stream>>>(wsi + WS_COUNTS, ws);
        k_final<<<1, 256, 0, stream>>>(ws, out, 1);
    } else {
        hipMemsetAsync(d_ws, 0, WS_ZERO_FLOATS * sizeof(float), stream);
        k_hist<<<64, 512, 0, stream>>>(labels, wsi + WS_COUNTS);
        k_scan<<<1, 64, 0, stream>>>(wsi + WS_COUNTS, wsi + WS_CURSOR,
                                     wsi + WS_POFFP, wsi + WS_EOFF);
        k_scatter<<<64, 512, 0, stream>>>(labels, wsi + WS_CURSOR, wsi + WS_PERM);
        k_stats<<<64, 256, 0, stream>>>(za, zb, labels, ws);
        k_gram_slow<<<dim3(3, C, 2), 256, 0, stream>>>(za, zb, wsi + WS_PERM,
                                                       wsi + WS_COUNTS, ws);
        k_final<<<1, 256, 0, stream>>>(ws, out, 0);
    }
}